// Round 1
// baseline (668.812 us; speedup 1.0000x reference)
//
#include <hip/hip_runtime.h>
#include <math.h>

#define BLOCK 256
#define IPB 2   // images per block

__device__ __forceinline__ void load_w25(const float* __restrict__ wp, float (&w)[25]) {
#pragma unroll
    for (int q = 0; q < 6; q++) {
        float4 v = *(const float4*)(wp + 4*q);
        w[4*q+0] = v.x; w[4*q+1] = v.y; w[4*q+2] = v.z; w[4*q+3] = v.w;
    }
    w[24] = wp[24];
}

// Fused per-image LeNet: conv1+pool -> conv2+pool -> fc1 -> fc2 -> fc3(emb)
__global__ __launch_bounds__(BLOCK, 2) void lenet_fused(
    const float* __restrict__ x,
    const float* __restrict__ c1w, const float* __restrict__ c1b,
    const float* __restrict__ c2w, const float* __restrict__ c2b,
    const float* __restrict__ f1w, const float* __restrict__ f1b,
    const float* __restrict__ f2w, const float* __restrict__ f2b,
    const float* __restrict__ f3w, const float* __restrict__ f3b,
    float* __restrict__ emb_out)
{
    __shared__ __align__(16) float img_s[IPB][3][32][32];   // 24576 B
    __shared__ __align__(16) float c1w_s[6][3][28];          // padded rows (16B-aligned per (c,ci))
    __shared__ __align__(16) float c2w_s[16][6][28];
    __shared__ __align__(16) float p1_s[IPB][6][14][14];
    __shared__ __align__(16) float p2_s[IPB][400];
    __shared__ __align__(16) float a1_s[IPB][120];
    __shared__ __align__(16) float a2_s[IPB][84];
    __shared__ float c1b_s[6];
    __shared__ float c2b_s[16];

    const int t = threadIdx.x;

    // ---- stage conv weights into padded LDS ----
    float* c1p = &c1w_s[0][0][0];
    for (int idx = t; idx < 450; idx += BLOCK) { int k = idx % 25, r = idx / 25; c1p[r*28 + k] = c1w[idx]; }
    float* c2p = &c2w_s[0][0][0];
    for (int idx = t; idx < 2400; idx += BLOCK) { int k = idx % 25, r = idx / 25; c2p[r*28 + k] = c2w[idx]; }
    if (t < 6)  c1b_s[t] = c1b[t];
    if (t < 16) c2b_s[t] = c2b[t];

    // ---- stage images (coalesced float4) ----
    const float4* xin = (const float4*)(x + (size_t)blockIdx.x * (IPB*3072));
    float4* ip = (float4*)&img_s[0][0][0][0];
    for (int idx = t; idx < IPB*768; idx += BLOCK) ip[idx] = xin[idx];
    __syncthreads();

    // ---- conv1 + relu + pool2 : [3,32,32] -> [6,14,14] ----
    // work item = (i, c, py, pp): 2 pooled outputs (conv patch 2 rows x 4 cols)
    for (int item = t; item < IPB*6*14*7; item += BLOCK) {
        int pp = item % 7;
        int rem = item / 7;
        int py = rem % 14; rem /= 14;
        int c = rem % 6;
        int i = rem / 6;
        const int y0 = py*2, x0 = pp*4;
        float acc[2][4] = {{0.f,0.f,0.f,0.f},{0.f,0.f,0.f,0.f}};
#pragma unroll
        for (int ci = 0; ci < 3; ci++) {
            float w[25];
            load_w25(&c1w_s[c][ci][0], w);
#pragma unroll
            for (int iy = 0; iy < 6; iy++) {
                const float* rp = &img_s[i][ci][y0+iy][x0];
                float4 va = *(const float4*)rp;
                float4 vb = *(const float4*)(rp+4);
                float r8[8] = {va.x,va.y,va.z,va.w,vb.x,vb.y,vb.z,vb.w};
#pragma unroll
                for (int cr = 0; cr < 2; cr++) {
                    const int ky = iy - cr;
                    if (ky >= 0 && ky < 5) {
#pragma unroll
                        for (int kx = 0; kx < 5; kx++)
#pragma unroll
                            for (int cx = 0; cx < 4; cx++)
                                acc[cr][cx] += w[ky*5+kx] * r8[kx+cx];
                    }
                }
            }
        }
        const float b = c1b_s[c];
        float m0 = fmaxf(fmaxf(acc[0][0], acc[0][1]), fmaxf(acc[1][0], acc[1][1]));
        float m1 = fmaxf(fmaxf(acc[0][2], acc[0][3]), fmaxf(acc[1][2], acc[1][3]));
        p1_s[i][c][py][pp*2+0] = fmaxf(m0 + b, 0.f);
        p1_s[i][c][py][pp*2+1] = fmaxf(m1 + b, 0.f);
    }
    __syncthreads();

    // ---- conv2 + relu + pool2 : [6,14,14] -> [16,5,5] ----
    // work item = (i, co, py, px): 1 pooled output (conv patch 2x2)
    for (int item = t; item < IPB*16*25; item += BLOCK) {
        int px = item % 5;
        int rem = item / 5;
        int py = rem % 5; rem /= 5;
        int co = rem % 16;
        int i = rem / 16;
        const int y0 = py*2, x0 = px*2;
        float acc[2][2] = {{0.f,0.f},{0.f,0.f}};
#pragma unroll
        for (int ci = 0; ci < 6; ci++) {
            float w[25];
            load_w25(&c2w_s[co][ci][0], w);
#pragma unroll
            for (int iy = 0; iy < 6; iy++) {
                const float* rp = &p1_s[i][ci][y0+iy][x0];
                float2 va = *(const float2*)rp;
                float2 vb = *(const float2*)(rp+2);
                float2 vc = *(const float2*)(rp+4);
                float r6[6] = {va.x,va.y,vb.x,vb.y,vc.x,vc.y};
#pragma unroll
                for (int cr = 0; cr < 2; cr++) {
                    const int ky = iy - cr;
                    if (ky >= 0 && ky < 5) {
#pragma unroll
                        for (int kx = 0; kx < 5; kx++)
#pragma unroll
                            for (int cx = 0; cx < 2; cx++)
                                acc[cr][cx] += w[ky*5+kx] * r6[kx+cx];
                    }
                }
            }
        }
        const float b = c2b_s[co];
        float mv = fmaxf(fmaxf(acc[0][0], acc[0][1]), fmaxf(acc[1][0], acc[1][1]));
        p2_s[i][co*25 + py*5 + px] = fmaxf(mv + b, 0.f);   // flatten = c*25+y*5+x
    }
    __syncthreads();

    // ---- fc1: 400 -> 120, relu ----
    if (t < IPB*120) {
        int o = t % 120, i = t / 120;
        float acc = f1b[o];
        const float4* wr = (const float4*)(f1w + o*400);
        const float4* ar = (const float4*)&p2_s[i][0];
#pragma unroll 5
        for (int k = 0; k < 100; k++) {
            float4 w4 = wr[k], a4 = ar[k];
            acc += w4.x*a4.x + w4.y*a4.y + w4.z*a4.z + w4.w*a4.w;
        }
        a1_s[i][o] = fmaxf(acc, 0.f);
    }
    __syncthreads();

    // ---- fc2: 120 -> 84, relu ----
    if (t < IPB*84) {
        int o = t % 84, i = t / 84;
        float acc = f2b[o];
        const float4* wr = (const float4*)(f2w + o*120);
        const float4* ar = (const float4*)&a1_s[i][0];
#pragma unroll
        for (int k = 0; k < 30; k++) {
            float4 w4 = wr[k], a4 = ar[k];
            acc += w4.x*a4.x + w4.y*a4.y + w4.z*a4.z + w4.w*a4.w;
        }
        a2_s[i][o] = fmaxf(acc, 0.f);
    }
    __syncthreads();

    // ---- fc3: 84 -> 64 (embeddings) ----
    if (t < IPB*64) {
        int o = t % 64, i = t / 64;
        float acc = f3b[o];
        const float4* wr = (const float4*)(f3w + o*84);
        const float4* ar = (const float4*)&a2_s[i][0];
#pragma unroll
        for (int k = 0; k < 21; k++) {
            float4 w4 = wr[k], a4 = ar[k];
            acc += w4.x*a4.x + w4.y*a4.y + w4.z*a4.z + w4.w*a4.w;
        }
        emb_out[((size_t)blockIdx.x*IPB + i)*64 + o] = acc;
    }
}

// Stage 1 of deterministic sum over all N*64 embeddings
__global__ __launch_bounds__(256) void reduce_emb(const float* __restrict__ emb,
                                                  float* __restrict__ part, int total) {
    __shared__ float s_[256];
    const int t = threadIdx.x;
    const int chunk = total / 256;              // 5120 for N=20480
    const float* base = emb + (size_t)blockIdx.x * chunk;
    float s = 0.f;
    for (int j = t; j < chunk; j += 256) s += base[j];
    s_[t] = s; __syncthreads();
    for (int off = 128; off > 0; off >>= 1) {
        if (t < off) s_[t] += s_[t + off];
        __syncthreads();
    }
    if (t == 0) part[blockIdx.x] = s_[0];
}

// Stage 2: 256 partials -> proto = sum / NUM_CLASSES
__global__ __launch_bounds__(256) void reduce_part(const float* __restrict__ part,
                                                   float* __restrict__ proto) {
    __shared__ float s_[256];
    const int t = threadIdx.x;
    s_[t] = part[t]; __syncthreads();
    for (int off = 128; off > 0; off >>= 1) {
        if (t < off) s_[t] += s_[t + off];
        __syncthreads();
    }
    if (t == 0) proto[0] = s_[0] / 5.0f;
}

// Per-row softmax over 64, then |softmax - proto|, in place on d_out
__global__ __launch_bounds__(256) void softmax_abs(float* __restrict__ io,
                                                   const float* __restrict__ proto_p) {
    const int lane = threadIdx.x & 63;
    const int row = (blockIdx.x << 2) + (threadIdx.x >> 6);
    const float proto = proto_p[0];
    float e = io[(size_t)row*64 + lane];
    float m = e;
#pragma unroll
    for (int off = 32; off; off >>= 1) m = fmaxf(m, __shfl_xor(m, off));
    float p = expf(e - m);
    float s = p;
#pragma unroll
    for (int off = 32; off; off >>= 1) s += __shfl_xor(s, off);
    io[(size_t)row*64 + lane] = fabsf(p / s - proto);
}

extern "C" void kernel_launch(void* const* d_in, const int* in_sizes, int n_in,
                              void* d_out, int out_size, void* d_ws, size_t ws_size,
                              hipStream_t stream) {
    const float* x   = (const float*)d_in[0];
    const float* c1w = (const float*)d_in[1];
    const float* c1b = (const float*)d_in[2];
    const float* c2w = (const float*)d_in[3];
    const float* c2b = (const float*)d_in[4];
    const float* f1w = (const float*)d_in[5];
    const float* f1b = (const float*)d_in[6];
    const float* f2w = (const float*)d_in[7];
    const float* f2b = (const float*)d_in[8];
    const float* f3w = (const float*)d_in[9];
    const float* f3b = (const float*)d_in[10];
    float* out = (float*)d_out;

    float* part  = (float*)d_ws;   // 256 floats
    float* proto = part + 256;     // 1 float

    const int N = in_sizes[0] / 3072;   // 20480
    const int total = N * 64;

    lenet_fused<<<N/IPB, BLOCK, 0, stream>>>(x, c1w, c1b, c2w, c2b,
                                             f1w, f1b, f2w, f2b, f3w, f3b, out);
    reduce_emb<<<256, 256, 0, stream>>>(out, part, total);
    reduce_part<<<1, 256, 0, stream>>>(part, proto);
    softmax_abs<<<N/4, 256, 0, stream>>>(out, proto);
}